// Round 12
// baseline (290.772 us; speedup 1.0000x reference)
//
#include <hip/hip_runtime.h>
#include <math.h>

typedef __bf16 bf16;
typedef __bf16 bf16x4 __attribute__((ext_vector_type(4)));
typedef __bf16 bf16x8 __attribute__((ext_vector_type(8)));
typedef float floatx4 __attribute__((ext_vector_type(4)));

#define MFMA16(a, b, c) __builtin_amdgcn_mfma_f32_16x16x32_bf16(a, b, c, 0, 0, 0)

#if __has_builtin(__builtin_amdgcn_exp2f)
#define EXP2F(x) __builtin_amdgcn_exp2f(x)
#else
#define EXP2F(x) exp2f(x)
#endif

constexpr int Bc = 4, SQc = 2048, SKVc = 2048, Hc = 16, Dc = 64;
// fold 1/sqrt(D) * log2(e) into qh so softmax is exp2 with no extra mul
#define QSCALE 0.18033688011112042f

// Fragment-order mapping for an [R][K] bf16 matrix consumed as MFMA frags:
//   elem (r,k) -> elem_idx = (r>>4)*(K/32)*512 + (k>>5)*512
//                 + ((k>>3)&3)*128 + (r&15)*8 + (k&7)
// A wave's fragment load is then base + 8*lane (16B/lane, 1KB contiguous).
// This is the exact mapping already verified end-to-end for attn's kk.

// Async global->LDS, 16B per lane (attn staging only).
__device__ __forceinline__ void glds16(const bf16* g, bf16* lds_base, int lane) {
#if __has_builtin(__builtin_amdgcn_global_load_lds)
  __builtin_amdgcn_global_load_lds(
      (const __attribute__((address_space(1))) void*)g,
      (__attribute__((address_space(3))) void*)lds_base, 16, 0, 0);
#else
  *(bf16x8*)(lds_base + 8 * lane) = *(const bf16x8*)g;
#endif
}

// ---------------------------------------------------------------------------
// Prepass: fp32 [8192][1024] -> bf16 in A-fragment order. Block = one row.
// ---------------------------------------------------------------------------
__global__ void cvt_bf16_frag(const float* __restrict__ in,
                              bf16* __restrict__ out) {
  const int row = blockIdx.x;
  const int k = threadIdx.x * 4;
  const float4 v = *(const float4*)&in[(size_t)row * 1024 + k];
  bf16x4 o = {(bf16)v.x, (bf16)v.y, (bf16)v.z, (bf16)v.w};
  const size_t idx = (size_t)(row >> 4) * 16384 + (k >> 5) * 512 +
                     ((k >> 3) & 3) * 128 + (row & 15) * 8 + (k & 7);
  *(bf16x4*)&out[idx] = o;
}

// ---------------------------------------------------------------------------
// Prepass: RoPE cos/sin table. tab[pos*32 + f] = (cos, sin) of
// ang = pos * 2^(-0.375 f).
// ---------------------------------------------------------------------------
__global__ void rope_tab_build(float2* __restrict__ tab) {
  const int i = blockIdx.x * 256 + threadIdx.x;  // 65536 = 2048 * 32
  const int pos = i >> 5, f = i & 31;
  const float ang = (float)pos * exp2f(-0.375f * (float)f);
  float sn, cs;
  sincosf(ang, &sn, &cs);
  tab[i] = make_float2(cs, sn);
}

// ---------------------------------------------------------------------------
// Prepass: W [K][N] fp32 -> WT in B-fragment order ([N][K] frag layout).
// grid (N/64, K/64), 256 thr.
// ---------------------------------------------------------------------------
__global__ void transpose_cvt(const float* __restrict__ in, bf16* __restrict__ out,
                              int K, int N) {
  __shared__ bf16 T[64][72];
  const int tid = threadIdx.x;
  const int n0 = blockIdx.x * 64, k0 = blockIdx.y * 64;
  const int tr = tid >> 4, tc4 = (tid & 15) * 4;
#pragma unroll
  for (int i = 0; i < 4; i++) {
    const int k = tr + 16 * i;
    const float4 v = *(const float4*)&in[(size_t)(k0 + k) * N + n0 + tc4];
    T[tc4 + 0][k] = (bf16)v.x;
    T[tc4 + 1][k] = (bf16)v.y;
    T[tc4 + 2][k] = (bf16)v.z;
    T[tc4 + 3][k] = (bf16)v.w;
  }
  __syncthreads();
  const int nr = tid >> 2, kc = (tid & 3) * 8;
#pragma unroll
  for (int hf = 0; hf < 2; hf++) {
    const int n = n0 + nr, k = k0 + kc + 32 * hf;
    const size_t idx = (size_t)((n >> 4) * (K >> 5) + (k >> 5)) * 512 +
                       ((k >> 3) & 3) * 128 + (n & 15) * 8;
    *(bf16x8*)&out[idx] = *(const bf16x8*)&T[nr][kc + 32 * hf];
  }
}

// ---------------------------------------------------------------------------
// Fragment-direct GEMM K-loop (attn-v8 style): no LDS, no barriers. Wave owns
// a 64x64 output tile; A frags loaded at iter top (attn's V pattern), B frags
// prefetched one step ahead (attn's K pattern); 32 MFMA per step.
// Ab/Bb are wave-local fragment bases (already + 8*lane).
// ---------------------------------------------------------------------------
__device__ __forceinline__ void gemm_fd_loop(const bf16* __restrict__ Ab,
                                             const bf16* __restrict__ Bb,
                                             floatx4 (*acc)[4]) {
  bf16x8 bfr[4][2];
#pragma unroll
  for (int j = 0; j < 4; j++) {
    bfr[j][0] = *(const bf16x8*)(Bb + (size_t)j * 16384);
    bfr[j][1] = *(const bf16x8*)(Bb + (size_t)j * 16384 + 512);
  }
  for (int t = 0; t < 16; ++t) {
    const size_t c = (size_t)(2 * t) * 512;
    // A fragments for this step
    bf16x8 af[4][2];
#pragma unroll
    for (int i = 0; i < 4; i++) {
      af[i][0] = *(const bf16x8*)(Ab + (size_t)i * 16384 + c);
      af[i][1] = *(const bf16x8*)(Ab + (size_t)i * 16384 + c + 512);
    }
    // B prefetch for next step
    bf16x8 bn[4][2];
    if (t < 15) {
#pragma unroll
      for (int j = 0; j < 4; j++) {
        bn[j][0] = *(const bf16x8*)(Bb + (size_t)j * 16384 + c + 1024);
        bn[j][1] = *(const bf16x8*)(Bb + (size_t)j * 16384 + c + 1536);
      }
    }
#pragma unroll
    for (int i = 0; i < 4; i++)
#pragma unroll
      for (int j = 0; j < 4; j++) {
        acc[i][j] = MFMA16(af[i][0], bfr[j][0], acc[i][j]);
        acc[i][j] = MFMA16(af[i][1], bfr[j][1], acc[i][j]);
      }
    if (t < 15) {
#pragma unroll
      for (int j = 0; j < 4; j++) {
        bfr[j][0] = bn[j][0];
        bfr[j][1] = bn[j][1];
      }
    }
  }
}

// ---------------------------------------------------------------------------
// Fused Q-proj + KV-proj, fragment-direct. grid (32, 18): y<16 -> Q tiles
// (RoPE+QSCALE -> qh), y==16 -> K cols (RoPE -> kko frag order),
// y==17 -> V cols (-> vto frag order). Block = 256x64 output (4 waves x 64M).
// ---------------------------------------------------------------------------
__global__ __launch_bounds__(256, 2) void gemm_qkv(
    const bf16* __restrict__ qA, const bf16* __restrict__ qBT,
    const float* __restrict__ qb, const bf16* __restrict__ kvA,
    const bf16* __restrict__ kvBT, const float* __restrict__ kvb,
    const float2* __restrict__ tab, bf16* __restrict__ qh,
    bf16* __restrict__ kko, bf16* __restrict__ vto) {
  const int tid = threadIdx.x, lane = tid & 63, wave = tid >> 6;
  const int m = lane & 15, g = lane >> 4;
  const int m0 = blockIdx.x * 256;
  const int mode = (blockIdx.y < 16) ? 0 : (blockIdx.y == 16 ? 1 : 2);
  const bf16* A = (mode == 0) ? qA : kvA;
  const bf16* BT = (mode == 0) ? qBT : kvBT;
  const int nb = (mode == 0) ? blockIdx.y * 64 : (mode == 1 ? 0 : 64);

  const bf16* Ab = A + (size_t)((m0 + wave * 64) >> 4) * 16384 + 8 * lane;
  const bf16* Bb = BT + (size_t)(nb >> 4) * 16384 + 8 * lane;

  floatx4 z = {0.f, 0.f, 0.f, 0.f};
  floatx4 acc[4][4];
#pragma unroll
  for (int i = 0; i < 4; i++)
#pragma unroll
    for (int j = 0; j < 4; j++) acc[i][j] = z;

  gemm_fd_loop(Ab, Bb, acc);

  const int rq = 4 * g;
#pragma unroll
  for (int j = 0; j < 4; j++) {
    const int col = nb + 16 * j + m;
    const float bv = (mode == 0) ? qb[col] : kvb[col];
#pragma unroll
    for (int i = 0; i < 4; i++) {
#pragma unroll
      for (int r = 0; r < 4; r++) {
        const int row = m0 + wave * 64 + 16 * i + rq + r;
        float v = acc[i][j][r] + bv;
        const float vp = __shfl_xor(v, 1);
        const int pos = row & (SQc - 1), b = row >> 11;
        if (mode == 0) {
          const int d = col & 63, hh = col >> 6;
          const float2 cssn = tab[pos * 32 + (d >> 1)];
          const float res = (d & 1) ? (v * cssn.x + vp * cssn.y)
                                    : (v * cssn.x - vp * cssn.y);
          qh[(((size_t)(b * Hc + hh) * SQc) + pos) * Dc + d] = (bf16)(res * QSCALE);
        } else if (mode == 1) {  // K with RoPE, fragment order
          const int d = 16 * j + m;
          const float2 cssn = tab[pos * 32 + (d >> 1)];
          const float res = (d & 1) ? (v * cssn.x + vp * cssn.y)
                                    : (v * cssn.x - vp * cssn.y);
          const size_t fb = (size_t)b * (SKVc * Dc);
          const int kc = (pos >> 4) * 2 + (d >> 5);
          const int kl = ((d >> 3) & 3) * 16 + (pos & 15);
          kko[fb + (size_t)kc * 512 + kl * 8 + (d & 7)] = (bf16)res;
        } else {  // V, fragment order
          const int d = 16 * j + m;
          const size_t fb = (size_t)b * (SKVc * Dc);
          const int vc = (pos >> 6) * 8 + (d >> 4) * 2 + ((pos >> 5) & 1);
          const int vl = ((pos >> 3) & 3) * 16 + (d & 15);
          vto[fb + (size_t)vc * 512 + vl * 8 + (pos & 7)] = (bf16)v;
        }
      }
    }
  }
}

// ---------------------------------------------------------------------------
// O-projection, fragment-direct: fp32 out. grid (32, 16).
// ---------------------------------------------------------------------------
__global__ __launch_bounds__(256, 2) void gemm_out(
    const bf16* __restrict__ A, const bf16* __restrict__ BT,
    const float* __restrict__ bias, float* __restrict__ out) {
  const int tid = threadIdx.x, lane = tid & 63, wave = tid >> 6;
  const int m = lane & 15, g = lane >> 4;
  const int m0 = blockIdx.x * 256, n0 = blockIdx.y * 64;

  const bf16* Ab = A + (size_t)((m0 + wave * 64) >> 4) * 16384 + 8 * lane;
  const bf16* Bb = BT + (size_t)(n0 >> 4) * 16384 + 8 * lane;

  floatx4 z = {0.f, 0.f, 0.f, 0.f};
  floatx4 acc[4][4];
#pragma unroll
  for (int i = 0; i < 4; i++)
#pragma unroll
    for (int j = 0; j < 4; j++) acc[i][j] = z;

  gemm_fd_loop(Ab, Bb, acc);

  const int rq = 4 * g;
#pragma unroll
  for (int j = 0; j < 4; j++) {
    const int col = n0 + 16 * j + m;
    const float bv = bias[col];
#pragma unroll
    for (int i = 0; i < 4; i++)
#pragma unroll
      for (int r = 0; r < 4; r++) {
        const int row = m0 + wave * 64 + 16 * i + rq + r;
        out[(size_t)row * 1024 + col] = acc[i][j][r] + bv;
      }
  }
}

// ---------------------------------------------------------------------------
// Flash attention v10 + T5 setprio (structure unchanged from R10): LDS-shared
// K/V, 8-wave blocks, 32 q-rows/wave, grid 512. ONLY change: hh written in
// A-fragment order so gemm_out can fragment-direct-load it.
// ---------------------------------------------------------------------------
__global__ __launch_bounds__(512, 4) void attn_v5(
    const bf16* __restrict__ qh, const bf16* __restrict__ kk,
    const bf16* __restrict__ vt, bf16* __restrict__ hout) {
  const int bid = blockIdx.x;
  const int qt = bid & 7, h = (bid >> 3) & 15, b = bid >> 7;
  const int tid = threadIdx.x, lane = tid & 63, wave = tid >> 6;  // 8 waves
  const int m = lane & 15, g = lane >> 4;

  __shared__ bf16 Kb[2][4096];       // 16 KiB: K tile double buffer
  __shared__ bf16 Vb[4096];          // 8 KiB: V tile
  __shared__ bf16 Pb[8][2][16][68];  // 34 KiB: per-wave private P relayout

  const int q0 = qt * 256 + wave * 32;
  // Q fragments (B-operand: n=q in lane&15, k=d)
  const bf16* qp = qh + (((size_t)(b * Hc + h) * SQc) + q0 + m) * Dc + 8 * g;
  bf16x8 bq[2][2];
#pragma unroll
  for (int s = 0; s < 2; s++) {
    bq[s][0] = *(const bf16x8*)(qp + (size_t)(16 * s) * Dc);
    bq[s][1] = *(const bf16x8*)(qp + (size_t)(16 * s) * Dc + 32);
  }

  const bf16 one = (bf16)1.0f;
  const bf16x8 ones = {one, one, one, one, one, one, one, one};

  floatx4 z = {0.f, 0.f, 0.f, 0.f};
  floatx4 accO[2][4];
  floatx4 lacc[2] = {z, z};
#pragma unroll
  for (int s = 0; s < 2; s++)
#pragma unroll
    for (int t = 0; t < 4; t++) accO[s][t] = z;

  // fragment-ordered global bases (per-lane: +16B*lane)
  const size_t fb = (size_t)b * (SKVc * Dc);
  const bf16* kg = kk + fb + 8 * lane;
  const bf16* vg = vt + fb + 8 * lane;

  // prologue: stage K(0); wave w stages chunk w (1 KiB each)
  glds16(kg + (size_t)wave * 512, &Kb[0][wave * 512], lane);
  __syncthreads();

  for (int it = 0; it < 32; ++it) {
    const int cur = it & 1;
    // top barrier: previous iter's Vb reads complete before restaging
    if (it) __syncthreads();
    // stage V(it) and K(it+1): wave w handles chunk w of each
    glds16(vg + (size_t)(it * 8 + wave) * 512, &Vb[wave * 512], lane);
    if (it + 1 < 32)
      glds16(kg + (size_t)((it + 1) * 8 + wave) * 512, &Kb[cur ^ 1][wave * 512],
             lane);

    // ---- phase 1: QK + exp2 + Pb write (K tile shared from LDS) ----
    bf16x8 kfr[4][2];
#pragma unroll
    for (int c = 0; c < 4; c++) {
      kfr[c][0] = *(const bf16x8*)&Kb[cur][(2 * c + 0) * 512 + 8 * lane];
      kfr[c][1] = *(const bf16x8*)&Kb[cur][(2 * c + 1) * 512 + 8 * lane];
    }
#pragma unroll
    for (int s = 0; s < 2; s++) {
#pragma unroll
      for (int c = 0; c < 4; c++) {
        floatx4 sv = MFMA16(kfr[c][0], bq[s][0], z);
        sv = MFMA16(kfr[c][1], bq[s][1], sv);
        bf16x4 pk = {(bf16)EXP2F(sv[0]), (bf16)EXP2F(sv[1]), (bf16)EXP2F(sv[2]),
                     (bf16)EXP2F(sv[3])};
        *(bf16x4*)&Pb[wave][s][m][16 * c + 4 * g] = pk;
      }
    }
    __syncthreads();  // drains vmcnt: V(it)/K(it+1) landed; Kb[cur] reads done

    // ---- phase 2: read V fragments from LDS, P from Pb, accumulate ----
    bf16x8 vf[4][2];
#pragma unroll
    for (int t = 0; t < 4; t++) {
      vf[t][0] = *(const bf16x8*)&Vb[(2 * t + 0) * 512 + 8 * lane];
      vf[t][1] = *(const bf16x8*)&Vb[(2 * t + 1) * 512 + 8 * lane];
    }
    __builtin_amdgcn_s_setprio(1);
#pragma unroll
    for (int s = 0; s < 2; s++) {
      const bf16x8 pa0 = *(const bf16x8*)&Pb[wave][s][m][8 * g];
      const bf16x8 pa1 = *(const bf16x8*)&Pb[wave][s][m][32 + 8 * g];
      lacc[s] = MFMA16(pa0, ones, lacc[s]);
      lacc[s] = MFMA16(pa1, ones, lacc[s]);
#pragma unroll
      for (int t = 0; t < 4; t++) {
        accO[s][t] = MFMA16(pa0, vf[t][0], accO[s][t]);
        accO[s][t] = MFMA16(pa1, vf[t][1], accO[s][t]);
      }
    }
    __builtin_amdgcn_s_setprio(0);
  }

  // ---- normalize and store hh in A-fragment order ----
#pragma unroll
  for (int s = 0; s < 2; s++) {
    floatx4 inv;
#pragma unroll
    for (int r = 0; r < 4; r++) inv[r] = 1.0f / lacc[s][r];
#pragma unroll
    for (int t = 0; t < 4; t++)
#pragma unroll
      for (int r = 0; r < 4; r++) {
        const int qrow = q0 + 16 * s + 4 * g + r;
        const int row = b * SQc + qrow;
        const int col = h * 64 + 16 * t + m;
        const size_t idx = (size_t)(row >> 4) * 16384 + (col >> 5) * 512 +
                           ((col >> 3) & 3) * 128 + (row & 15) * 8 + (col & 7);
        hout[idx] = (bf16)(accO[s][t][r] * inv[r]);
      }
  }
}

// ---------------------------------------------------------------------------
extern "C" void kernel_launch(void* const* d_in, const int* in_sizes, int n_in,
                              void* d_out, int out_size, void* d_ws, size_t ws_size,
                              hipStream_t stream) {
  const float* q = (const float*)d_in[0];
  const float* kv = (const float*)d_in[1];
  const float* Wq = (const float*)d_in[2];
  const float* bq = (const float*)d_in[3];
  const float* Wkv = (const float*)d_in[4];
  const float* bkv = (const float*)d_in[5];
  const float* Wo = (const float*)d_in[6];
  const float* bo = (const float*)d_in[7];

  char* ws = (char*)d_ws;
  bf16* qbf = (bf16*)ws;                            // 16 MiB (reused as hh later)
  bf16* kvbf = (bf16*)(ws + ((size_t)16 << 20));    // 16 MiB
  bf16* WqT = (bf16*)(ws + ((size_t)32 << 20));     // 2 MiB
  bf16* WkvT = (bf16*)(ws + ((size_t)34 << 20));    // 256 KiB
  float2* rtab = (float2*)(ws + ((size_t)34 << 20) + ((size_t)256 << 10));  // 512 KiB
  bf16* WoT = (bf16*)(ws + ((size_t)35 << 20));     // 2 MiB
  bf16* qh = (bf16*)(ws + ((size_t)37 << 20));      // 16 MiB (linear)
  bf16* kk = (bf16*)(ws + ((size_t)53 << 20));      // 1 MiB (fragment order)
  bf16* vt = (bf16*)(ws + ((size_t)54 << 20));      // 1 MiB (fragment order)
  bf16* hh = qbf;  // alias: qbf dead after gemm_qkv; hh in fragment order

  const int M = Bc * SQc;  // 8192

  rope_tab_build<<<256, 256, 0, stream>>>(rtab);
  cvt_bf16_frag<<<M, 256, 0, stream>>>(q, qbf);
  cvt_bf16_frag<<<M, 256, 0, stream>>>(kv, kvbf);
  transpose_cvt<<<dim3(16, 16), 256, 0, stream>>>(Wq, WqT, 1024, 1024);
  transpose_cvt<<<dim3(2, 16), 256, 0, stream>>>(Wkv, WkvT, 1024, 128);
  transpose_cvt<<<dim3(16, 16), 256, 0, stream>>>(Wo, WoT, 1024, 1024);

  gemm_qkv<<<dim3(32, 18), 256, 0, stream>>>(qbf, WqT, bq, kvbf, WkvT, bkv, rtab,
                                             qh, kk, vt);
  attn_v5<<<Bc * Hc * (SQc / 256), 512, 0, stream>>>(qh, kk, vt, hh);
  gemm_out<<<dim3(32, 16), 256, 0, stream>>>(hh, WoT, bo, (float*)d_out);
}